// Round 10
// baseline (65.076 us; speedup 1.0000x reference)
//
#include <hip/hip_runtime.h>
#include <math.h>

#define N_SAMPLES 524288
#define A_ACT 8
#define D_DIM 64
#define E_DIM 32
#define LOG2PI_F 1.8378770664093453f

#define SORT_THREADS 256
#define CHUNK 512
#define NBLK (N_SAMPLES / CHUNK)      // 1024
#define HIST_SIZE (A_ACT * NBLK)      // 8192
#define SCAN_PER (HIST_SIZE / 256)    // 32

typedef __attribute__((ext_vector_type(8))) short bf16x8;
typedef __attribute__((ext_vector_type(4))) float f32x4;

__device__ __forceinline__ short f2bf(float f) {
  unsigned u = __float_as_uint(f);
  unsigned r = (u + 0x7FFFu + ((u >> 16) & 1u)) >> 16;
  return (short)r;
}

__device__ __forceinline__ bf16x8 pack8(float4 a, float4 b) {
  bf16x8 r;
  r[0] = f2bf(a.x); r[1] = f2bf(a.y); r[2] = f2bf(a.z); r[3] = f2bf(a.w);
  r[4] = f2bf(b.x); r[5] = f2bf(b.y); r[6] = f2bf(b.z); r[7] = f2bf(b.w);
  return r;
}

// ---------------- Kernel 1: per-chunk histogram ----------------
__global__ __launch_bounds__(SORT_THREADS) void hist_kernel(
    const int* __restrict__ idx, int* __restrict__ hist) {
  __shared__ int cnt[A_ACT];
  int t = threadIdx.x;
  if (t < A_ACT) cnt[t] = 0;
  __syncthreads();
  int base = blockIdx.x * CHUNK;
#pragma unroll
  for (int j = 0; j < CHUNK / SORT_THREADS; ++j) {
    atomicAdd(&cnt[idx[base + j * SORT_THREADS + t]], 1);
  }
  __syncthreads();
  if (t < A_ACT) hist[t * NBLK + blockIdx.x] = cnt[t];
}

// ---------------- Kernel 2: exclusive scan of hist (1 block) ----------------
__global__ __launch_bounds__(256) void scan_kernel(int* __restrict__ hist) {
  __shared__ int sums[256];
  int t = threadIdx.x;
  int vals[SCAN_PER];
  int s = 0;
#pragma unroll
  for (int k = 0; k < SCAN_PER; ++k) {
    vals[k] = hist[t * SCAN_PER + k];
    s += vals[k];
  }
  sums[t] = s;
  __syncthreads();
  for (int off = 1; off < 256; off <<= 1) {
    int v = (t >= off) ? sums[t - off] : 0;
    __syncthreads();
    sums[t] += v;
    __syncthreads();
  }
  int prefix = (t == 0) ? 0 : sums[t - 1];
#pragma unroll
  for (int k = 0; k < SCAN_PER; ++k) {
    int v = vals[k];
    hist[t * SCAN_PER + k] = prefix;
    prefix += v;
  }
}

// ---------------- Kernel 3: stable scatter (builds p and inv) ----------------
__global__ __launch_bounds__(SORT_THREADS) void scatter_kernel(
    const int* __restrict__ idx, const int* __restrict__ offs,
    int* __restrict__ p, int* __restrict__ inv) {
  __shared__ int base[A_ACT];
  __shared__ int wcnt[4][A_ACT];
  int t = threadIdx.x;
  int wave = t >> 6;
  int lane = t & 63;
  if (t < A_ACT) base[t] = offs[t * NBLK + blockIdx.x];
  __syncthreads();
  int cstart = blockIdx.x * CHUNK;
#pragma unroll
  for (int pass = 0; pass < CHUNK / SORT_THREADS; ++pass) {   // 2 passes
    int i = cstart + pass * SORT_THREADS + t;
    int a = idx[i];
    unsigned long long mymask = 0ULL;
#pragma unroll
    for (int aa = 0; aa < A_ACT; ++aa) {
      unsigned long long m = __ballot(a == aa);
      if (aa == a) mymask = m;
      if (lane == 0) wcnt[wave][aa] = __popcll(m);
    }
    unsigned long long below = (1ULL << lane) - 1ULL;
    int inwave = __popcll(mymask & below);
    __syncthreads();
    int wprefix = 0;
#pragma unroll
    for (int w = 0; w < 4; ++w)
      if (w < wave) wprefix += wcnt[w][a];
    int r = base[a] + wprefix + inwave;
    p[r] = i;
    inv[i] = r;
    __syncthreads();
    if (t < A_ACT) {
      int tot = 0;
#pragma unroll
      for (int w = 0; w < 4; ++w) tot += wcnt[w][t];
      base[t] += tot;
    }
    __syncthreads();
  }
}

// ---------------- Kernel 4: MFMA matvec + rsample + logprob ----------------
// One actor per block; 128 sorted rows. A-fragments gathered DIRECTLY from
// global state (lane l reads 32B of row p[...]; lanes l,l+16,l+32,l+48 cover
// one 128B half-row -> full line utilization, no LDS staging round-trip).
// B = W[a] bf16 in LDS (verified swizzle). acc -> LDS -> vectorized epilogue.
// eps/inv/bias prefetched into regs before MFMA to hide latency.
#define TILE_ROWS 128
#define MAIN_THREADS 256
#define MAIN_BLOCKS (N_SAMPLES / TILE_ROWS + A_ACT)

__global__ __launch_bounds__(MAIN_THREADS, 4) void main_kernel(
    const float* __restrict__ state, const float* __restrict__ W,
    const float* __restrict__ bias, const float* __restrict__ lstd,
    const float* __restrict__ eps, const int* __restrict__ p,
    const int* __restrict__ inv, const int* __restrict__ offs,
    float* __restrict__ out_action, float* __restrict__ out_lp) {
  __shared__ short sB[E_DIM * D_DIM];       // 4 KB bf16 [col][k], swizzled
  __shared__ float sC[TILE_ROWS * E_DIM];   // 16 KB fp32, chunk-swizzled

  int t = threadIdx.x;
  int bid = blockIdx.x;

  // Map block -> (actor, row chunk): each block serves exactly one actor.
  int a = -1, kbase = 0, kend = 0;
  int acc_b = 0;
#pragma unroll
  for (int aa = 0; aa < A_ACT; ++aa) {
    int start = offs[aa * NBLK];
    int end = (aa == A_ACT - 1) ? N_SAMPLES : offs[(aa + 1) * NBLK];
    int cnt = end - start;
    int nc = (cnt + TILE_ROWS - 1) / TILE_ROWS;
    if (a < 0 && bid < acc_b + nc) {
      a = aa;
      int chunk = bid - acc_b;
      kbase = start + chunk * TILE_ROWS;
      kend = min(end, kbase + TILE_ROWS);
    }
    acc_b += nc;
  }
  if (a < 0) return;  // uniform across block
  int nrows = kend - kbase;

  // Stage B: W[a] fp32 [d=k][e=col] -> sB bf16 [col][k], 16B-chunk swizzle.
  {
    int col = t >> 3;          // 0..31
    int kc = t & 7;            // k-chunk 0..7 (8 k's each)
    const float* wp = W + (size_t)a * (D_DIM * E_DIM) + (kc * 8) * E_DIM + col;
    bf16x8 v;
#pragma unroll
    for (int j = 0; j < 8; ++j) v[j] = f2bf(wp[j * E_DIM]);
    *(bf16x8*)(&sB[col * D_DIM + ((kc ^ (col & 7)) << 3)]) = v;
  }

  int w = t >> 6;
  int l = t & 63;
  int lrow = l & 15;   // A-row / B-col within tile
  int lk = l >> 4;     // k lane-group 0..3
  int r0 = w * 32;

  // A-row indices (16 consecutive p-values per row-tile; broadcast across
  // k-lane groups), then issue all 8 state gathers (max MLP).
  int mrow[2];
#pragma unroll
  for (int rt = 0; rt < 2; ++rt)
    mrow[rt] = p[kbase + min(r0 + rt * 16 + lrow, nrows - 1)];

  float4 av[2][2][2];
#pragma unroll
  for (int rt = 0; rt < 2; ++rt) {
#pragma unroll
    for (int ks = 0; ks < 2; ++ks) {
      const float* sp = state + (size_t)mrow[rt] * D_DIM + ks * 32 + lk * 8;
      av[rt][ks][0] = *(const float4*)sp;
      av[rt][ks][1] = *(const float4*)(sp + 4);
    }
  }

  // Prefetch epilogue data (coalesced; hidden under MFMA phase).
  int c = t & 7;            // col chunk 0..7 (4 cols)
  float4 epv[4];
  int dst[4];
#pragma unroll
  for (int pass = 0; pass < 4; ++pass) {
    int row = pass * 32 + (t >> 3);
    int rc = min(row, nrows - 1);
    epv[pass] = *(const float4*)(eps + (size_t)(kbase + rc) * E_DIM + c * 4);
    dst[pass] = inv[kbase + rc];
  }
  float4 bv = *(const float4*)(bias + a * E_DIM + c * 4);
  float4 lv = *(const float4*)(lstd + a * E_DIM + c * 4);

  __syncthreads();   // sB ready

  // Convert + MFMA.
  f32x4 acc[2][2];
#pragma unroll
  for (int rt = 0; rt < 2; ++rt)
#pragma unroll
    for (int ct = 0; ct < 2; ++ct) acc[rt][ct] = (f32x4){0.f, 0.f, 0.f, 0.f};

#pragma unroll
  for (int ks = 0; ks < 2; ++ks) {
    int kc = ks * 4 + lk;
    bf16x8 aF[2], bF[2];
#pragma unroll
    for (int rt = 0; rt < 2; ++rt)
      aF[rt] = pack8(av[rt][ks][0], av[rt][ks][1]);
#pragma unroll
    for (int ct = 0; ct < 2; ++ct) {
      int col = ct * 16 + lrow;
      bF[ct] = *(const bf16x8*)(&sB[col * D_DIM + ((kc ^ (col & 7)) << 3)]);
    }
#pragma unroll
    for (int rt = 0; rt < 2; ++rt)
#pragma unroll
      for (int ct = 0; ct < 2; ++ct)
        acc[rt][ct] = __builtin_amdgcn_mfma_f32_16x16x32_bf16(
            aF[rt], bF[ct], acc[rt][ct], 0, 0, 0);
  }

  // Dump acc to LDS. C/D layout: col = lane&15, row = (lane>>4)*4 + reg.
#pragma unroll
  for (int rt = 0; rt < 2; ++rt) {
#pragma unroll
    for (int ct = 0; ct < 2; ++ct) {
      int col = ct * 16 + lrow;
#pragma unroll
      for (int r = 0; r < 4; ++r) {
        int row = r0 + rt * 16 + lk * 4 + r;
        sC[row * E_DIM + (((col >> 2) ^ (row & 7)) << 2) + (col & 3)] =
            acc[rt][ct][r];
      }
    }
  }
  __syncthreads();

  // Vectorized epilogue: 8 lanes per row, float4 everywhere.
  const float bva[4] = {bv.x, bv.y, bv.z, bv.w};
  const float lsa[4] = {lv.x, lv.y, lv.z, lv.w};
  float sda[4];
#pragma unroll
  for (int j = 0; j < 4; ++j) sda[j] = expf(lsa[j]);
  float lsum = lsa[0] + lsa[1] + lsa[2] + lsa[3];

#pragma unroll
  for (int pass = 0; pass < 4; ++pass) {
    int row = pass * 32 + (t >> 3);
    bool valid = (row < nrows);
    int rcrow = valid ? row : (nrows - 1);
    float4 av2 = *(const float4*)(&sC[rcrow * E_DIM + ((c ^ (rcrow & 7)) << 2)]);
    const float ep[4] = {epv[pass].x, epv[pass].y, epv[pass].z, epv[pass].w};
    const float ac[4] = {av2.x, av2.y, av2.z, av2.w};
    float o[4];
    float part = -lsum;
#pragma unroll
    for (int j = 0; j < 4; ++j) {
      o[j] = fmaf(sda[j], ep[j], ac[j] + bva[j]);
      part = fmaf(-0.5f * ep[j], ep[j], part);
    }
    part += __shfl_xor(part, 1, 64);
    part += __shfl_xor(part, 2, 64);
    part += __shfl_xor(part, 4, 64);
    if (valid) {
      *(float4*)(&out_action[(size_t)dst[pass] * E_DIM + c * 4]) =
          make_float4(o[0], o[1], o[2], o[3]);
      if (c == 0) out_lp[dst[pass]] = part - 16.0f * LOG2PI_F;
    }
  }
}

extern "C" void kernel_launch(void* const* d_in, const int* in_sizes, int n_in,
                              void* d_out, int out_size, void* d_ws, size_t ws_size,
                              hipStream_t stream) {
  const float* state = (const float*)d_in[0];
  const float* W     = (const float*)d_in[1];
  const float* b     = (const float*)d_in[2];
  const float* ls    = (const float*)d_in[3];
  const float* eps   = (const float*)d_in[4];
  const int*   idx   = (const int*)d_in[5];

  float* out_action = (float*)d_out;                              // [N, E]
  float* out_lp     = (float*)d_out + (size_t)N_SAMPLES * E_DIM;  // [N]

  int* p    = (int*)d_ws;
  int* inv  = p + N_SAMPLES;
  int* hist = inv + N_SAMPLES;

  hipLaunchKernelGGL(hist_kernel, dim3(NBLK), dim3(SORT_THREADS), 0, stream,
                     idx, hist);
  hipLaunchKernelGGL(scan_kernel, dim3(1), dim3(256), 0, stream, hist);
  hipLaunchKernelGGL(scatter_kernel, dim3(NBLK), dim3(SORT_THREADS), 0, stream,
                     idx, hist, p, inv);
  hipLaunchKernelGGL(main_kernel, dim3(MAIN_BLOCKS), dim3(MAIN_THREADS),
                     0, stream, state, W, b, ls, eps, p, inv, hist,
                     out_action, out_lp);
}